// Round 6
// baseline (337.635 us; speedup 1.0000x reference)
//
#include <hip/hip_runtime.h>
#include <hip/hip_bf16.h>
#include <hip/hip_cooperative_groups.h>

namespace cg = cooperative_groups;

// Problem constants (ODST forward):
//   x    [B=1024, I=256]  fsl [I=256,N=512,D=6]  th/lt [N=512,D=6]
//   resp [N=512, U=16, C=64]   out [B=1024, U=16]
#define B_SZ 1024
#define I_SZ 256
#define N_SZ 512
#define D_SZ 6
#define U_SZ 16
#define C_SZ 64
#define NSPLIT 64            // 8 n (48 k' rows) per fused block

typedef __bf16 bf16_t;
typedef bf16_t bf16x8 __attribute__((ext_vector_type(8)));
typedef bf16_t bf16x4 __attribute__((ext_vector_type(4)));
typedef float  f32x4  __attribute__((ext_vector_type(4)));

// ---------------------------------------------------------------------------
// Single cooperative kernel: 1024 blocks x 256 threads (4 blocks/CU, 16
// waves/CU — co-resident by construction; launch_bounds(256,4) caps VGPR=128).
// Phase P: prep (x/resp -> bf16, elt=exp(-lt), sparsemax -> selT bf16
//          transposed), 1292 units strided over 1024 blocks.
// Phase F: per (btile, ns): 48k' x 64b feature-GEMM via MFMA -> LDS tl tile
//          (th/elt folded into epilogue), then tree eval: per-lane leaf-weight
//          A-frags + respb B-frags -> 2 MFMA per n -> part[ns][b][u].
// Phase R: blocks 0..255 reduce part over 64 ns -> out.
// Grid syncs replace 2 kernel-launch gaps; smem (13 KB) reused per phase.
// ---------------------------------------------------------------------------
__global__ __launch_bounds__(256, 4) void odst_coop(
    const float* __restrict__ x, const float* __restrict__ fsl,
    const float* __restrict__ th, const float* __restrict__ lt,
    const float* __restrict__ resp,
    bf16_t* __restrict__ xb, bf16_t* __restrict__ respb,
    float* __restrict__ elt, bf16_t* __restrict__ selT,
    float* __restrict__ part, float* __restrict__ out) {
  __shared__ float smem[48 * 68];       // 13056 B, reused by all phases
  cg::grid_group grid = cg::this_grid();
  const int bid = blockIdx.x, t = threadIdx.x;

  // ================= Phase P: prep =================
  for (int u = bid; u < 1292; u += 1024) {
    if (u < 256) {                                   // x -> bf16
      const int idx = (u * 256 + t) * 4;
      const float4 v = *(const float4*)(x + idx);
      bf16x4 o; o[0] = (bf16_t)v.x; o[1] = (bf16_t)v.y; o[2] = (bf16_t)v.z; o[3] = (bf16_t)v.w;
      *(bf16x4*)(xb + idx) = o;
    } else if (u < 768) {                            // resp -> bf16
      const int idx = ((u - 256) * 256 + t) * 4;
      const float4 v = *(const float4*)(resp + idx);
      bf16x4 o; o[0] = (bf16_t)v.x; o[1] = (bf16_t)v.y; o[2] = (bf16_t)v.z; o[3] = (bf16_t)v.w;
      *(bf16x4*)(respb + idx) = o;
    } else if (u < 780) {                            // elt = exp(-lt)
      const int i = (u - 768) * 256 + t;
      elt[i] = __expf(-lt[i]);
    } else {                                         // sparsemax -> selT
      float (*sT)[17] = (float(*)[17])smem;          // [96][17]
      const int sbid = u - 780;                      // 0..511
      const int i_loc = t >> 4, n_loc = t & 15;
      const int n0 = (sbid & 31) * 16, i0 = (sbid >> 5) * 16;

      const float* z = fsl + ((size_t)(i0 + i_loc) * N_SZ + (n0 + n_loc)) * D_SZ;
      float v[D_SZ], s[D_SZ];
#pragma unroll
      for (int d = 0; d < D_SZ; ++d) { v[d] = z[d]; s[d] = v[d]; }

#define CSWAP(a, b) { float hi = fmaxf(s[a], s[b]); float lo = fminf(s[a], s[b]); s[a] = hi; s[b] = lo; }
#pragma unroll
      for (int r = 0; r < 3; ++r) {
        CSWAP(0, 1) CSWAP(2, 3) CSWAP(4, 5)
        CSWAP(1, 2) CSWAP(3, 4)
      }
#undef CSWAP

      float cs[D_SZ];
      cs[0] = s[0];
#pragma unroll
      for (int j = 1; j < D_SZ; ++j) cs[j] = cs[j - 1] + s[j];
      int kz = 0;
#pragma unroll
      for (int j = 0; j < D_SZ; ++j)
        kz += (1.0f + (float)(j + 1) * s[j] > cs[j]) ? 1 : 0;
      const float tau = (cs[kz - 1] - 1.0f) / (float)kz;

#pragma unroll
      for (int d = 0; d < D_SZ; ++d)
        sT[n_loc * 6 + d][i_loc] = fmaxf(v[d] - tau, 0.0f);
      __syncthreads();

      if (t < 192) {
        const int row = t >> 1, half = t & 1;
        bf16x8 o;
#pragma unroll
        for (int jj = 0; jj < 8; ++jj) o[jj] = (bf16_t)sT[row][half * 8 + jj];
        *(bf16x8*)(selT + (size_t)(n0 * 6 + row) * I_SZ + i0 + half * 8) = o;
      }
    }
  }

  grid.sync();

  // ================= Phase F: fused GEMM + tree =================
  {
    float (*fv)[68] = (float(*)[68])smem;            // [48][68] = tl values
    const int lane = t & 63, wave = t >> 6;
    const int lm = lane & 15, q = lane >> 4;
    const int btile = bid & 15, ns = bid >> 4;

    // ---- GEMM 48 k' x 64 b (waves 0-2); epilogue folds th/elt -> tl in LDS
    if (wave < 3) {
      f32x4 acc[4];
#pragma unroll
      for (int s = 0; s < 4; ++s) acc[s] = (f32x4){0.f, 0.f, 0.f, 0.f};
      const bf16_t* arow = selT + (size_t)(ns * 48 + wave * 16 + lm) * I_SZ + q * 8;
      const bf16_t* brow = xb + (size_t)(btile * 64 + lm) * I_SZ + q * 8;
#pragma unroll
      for (int kk = 0; kk < I_SZ; kk += 32) {
        const bf16x8 a = *(const bf16x8*)(arow + kk);
#pragma unroll
        for (int s = 0; s < 4; ++s) {
          const bf16x8 bv = *(const bf16x8*)(brow + (size_t)s * 16 * I_SZ + kk);
          acc[s] = __builtin_amdgcn_mfma_f32_16x16x32_bf16(a, bv, acc[s], 0, 0, 0);
        }
      }
      float thv[4], ev[4];
#pragma unroll
      for (int r = 0; r < 4; ++r) {
        const int kp = ns * 48 + wave * 16 + q * 4 + r;
        thv[r] = th[kp]; ev[r] = elt[kp];
      }
      // C/D: row(k'_loc within 16) = q*4+r, col(b_loc within 16) = lm
#pragma unroll
      for (int s = 0; s < 4; ++s)
#pragma unroll
        for (int r = 0; r < 4; ++r)
          fv[wave * 16 + q * 4 + r][s * 16 + lm] = (acc[s][r] - thv[r]) * ev[r];
    }
    __syncthreads();

    // ---- tree eval: wave handles b_loc in [wave*16, +16)
    f32x4 acc = (f32x4){0.f, 0.f, 0.f, 0.f};
    const int bloc = wave * 16 + lm;

#pragma unroll
    for (int j = 0; j < 8; ++j) {
      const int n = ns * 8 + j;
      const bf16_t* rb = respb + (size_t)n * (U_SZ * C_SZ) + lm * C_SZ + q * 8;
      const bf16x8 bv0 = *(const bf16x8*)(rb);
      const bf16x8 bv1 = *(const bf16x8*)(rb + 32);

      float b0v[D_SZ], b1v[D_SZ];
#pragma unroll
      for (int d = 0; d < D_SZ; ++d) {
        const float tl = fv[j * 6 + d][bloc];
        b1v[d] = fminf(fmaxf(0.5f * tl + 0.5f, 0.0f), 1.0f);  // bit = 0
        b0v[d] = fminf(fmaxf(0.5f - 0.5f * tl, 0.0f), 1.0f);  // bit = 1
      }
      float p2[2], p4[4], p8[8];
      p2[0] = b1v[0]; p2[1] = b0v[0];
#pragma unroll
      for (int i = 0; i < 4; ++i) p4[i] = p2[i & 1] * ((i & 2) ? b0v[1] : b1v[1]);
#pragma unroll
      for (int i = 0; i < 8; ++i) p8[i] = p4[i & 3] * ((i & 4) ? b0v[2] : b1v[2]);
      const float f3 = (q & 1) ? b0v[3] : b1v[3];
      const float f4 = (q & 2) ? b0v[4] : b1v[4];
      const float fq = f3 * f4;
      const float g0 = fq * b1v[5];   // chunk 0: bit5 = 0
      const float g1 = fq * b0v[5];   // chunk 1: bit5 = 1

      bf16x8 a0, a1;
#pragma unroll
      for (int jj = 0; jj < 8; ++jj) {
        a0[jj] = (bf16_t)(p8[jj] * g0);
        a1[jj] = (bf16_t)(p8[jj] * g1);
      }
      acc = __builtin_amdgcn_mfma_f32_16x16x32_bf16(a0, bv0, acc, 0, 0, 0);
      acc = __builtin_amdgcn_mfma_f32_16x16x32_bf16(a1, bv1, acc, 0, 0, 0);
    }

    // C/D: col(u) = lm, row(b within 16) = q*4 + r
#pragma unroll
    for (int r = 0; r < 4; ++r)
      part[(size_t)ns * (B_SZ * U_SZ) +
           (size_t)(btile * 64 + wave * 16 + q * 4 + r) * U_SZ + lm] = acc[r];
  }

  grid.sync();

  // ================= Phase R: reduce (blocks 0..255) =================
  if (bid < 256) {
    float (*red)[64] = (float(*)[64])smem;
    const int o = bid * 64 + (t & 63);
    const int g = t >> 6;
    float s = 0.0f;
#pragma unroll
    for (int k = 0; k < 16; ++k)
      s += part[(size_t)(g * 16 + k) * (B_SZ * U_SZ) + o];
    red[g][t & 63] = s;
    __syncthreads();
    if (t < 64)
      out[bid * 64 + t] = red[0][t] + red[1][t] + red[2][t] + red[3][t];
  }
}

// ---------------------------------------------------------------------------
extern "C" void kernel_launch(void* const* d_in, const int* in_sizes, int n_in,
                              void* d_out, int out_size, void* d_ws, size_t ws_size,
                              hipStream_t stream) {
  const float* x    = (const float*)d_in[0];
  const float* fsl  = (const float*)d_in[1];
  const float* th   = (const float*)d_in[2];
  const float* lt   = (const float*)d_in[3];
  const float* resp = (const float*)d_in[4];
  float* out = (float*)d_out;

  // workspace (~7.4 MB)
  char* w = (char*)d_ws;
  bf16_t* xb    = (bf16_t*)(w);                 //  524288 B
  bf16_t* respb = (bf16_t*)(w + 524288);        // 1048576 B
  float*  elt   = (float*)(w + 1572864);        //   12288 B
  bf16_t* selT  = (bf16_t*)(w + 1585152);       // 1572864 B  [3072][256]
  float*  part  = (float*)(w + 3158016);        // 4194304 B  [64][16384]

  void* args[] = {(void*)&x, (void*)&fsl, (void*)&th, (void*)&lt, (void*)&resp,
                  (void*)&xb, (void*)&respb, (void*)&elt, (void*)&selT,
                  (void*)&part, (void*)&out};
  hipLaunchCooperativeKernel((void*)odst_coop, dim3(16 * NSPLIT), dim3(256),
                             args, 0, stream);
}

// Round 7
// 109.568 us; speedup vs baseline: 3.0815x; 3.0815x over previous
//
#include <hip/hip_runtime.h>
#include <hip/hip_bf16.h>

// Problem constants (ODST forward):
//   x    [B=1024, I=256]  fsl [I=256,N=512,D=6]  th/lt [N=512,D=6]
//   resp [N=512, U=16, C=64]   out [B=1024, U=16]
#define B_SZ 1024
#define I_SZ 256
#define N_SZ 512
#define D_SZ 6
#define U_SZ 16
#define C_SZ 64
#define NSPLIT 64            // 8 n (48 k' rows) per fused block

typedef __bf16 bf16_t;
typedef bf16_t bf16x8 __attribute__((ext_vector_type(8)));
typedef float  f32x4  __attribute__((ext_vector_type(4)));

#define SEL_P 264            // selS row pitch in bf16 (256 + 8 pad)

// ---------------------------------------------------------------------------
// Fused kernel, fully self-sufficient per block (no prep dispatch, no
// cooperative sync — R5's grid.sync cost ~100+ us per sync on 8 XCDs).
// Block (btile, ns): b in [btile*64,+64), n in [ns*8,+8) = 48 k' rows.
//  Phase S: in-block sparsemax for (all 256 i) x (8 n) -> LDS selS bf16
//           in A-operand layout. x16 btile redundancy ~= 2 us chip-wide.
//  Phase A: 48k' x 64b GEMM via MFMA. A-frags: ds_read_b128 from selS;
//           B-frags: x f32 direct + cvt. Epilogue folds th/exp(-lt) -> LDS fv.
//  Phase B: tree eval: bins from fv, per-lane leaf-weight A-frags
//           (c-bits: jj=0-2 frag, q=3-4 quad, chunk=5), resp f32+cvt B-frags,
//           2 MFMA per n -> part[ns][b][u].
// LDS 38.4 KB -> 4 blocks/CU; launch_bounds(256,4) keeps VGPR <= 128.
// ---------------------------------------------------------------------------
__global__ __launch_bounds__(256, 4) void fused_k(
    const float* __restrict__ x,      // [1024][256]
    const float* __restrict__ fsl,    // [256][512][6]
    const float* __restrict__ th,     // [512][6]
    const float* __restrict__ lt,     // [512][6]
    const float* __restrict__ resp,   // [512][16][64]
    float* __restrict__ part) {       // [64 ns][1024 b][16 u]
  __shared__ bf16_t selS[48 * SEL_P];   // 25344 B, A-operand tile [k'_loc][i]
  __shared__ float  fv[48][68];         // 13056 B, tl values [k'_loc][b_loc]
  const int t = threadIdx.x;
  const int lane = t & 63, wave = t >> 6;
  const int lm = lane & 15, q = lane >> 4;
  const int btile = blockIdx.x & 15, ns = blockIdx.x >> 4;

  // ---- Phase S: sparsemax for i = t, n = ns*8+j (j=0..7)
  {
    const float* zbase = fsl + (size_t)t * (N_SZ * D_SZ) + ns * 48;
    float v[48];
#pragma unroll
    for (int c = 0; c < 12; ++c) *(float4*)&v[c * 4] = *(const float4*)(zbase + c * 4);

#pragma unroll
    for (int j = 0; j < 8; ++j) {
      float* z = v + j * 6;
      float s[D_SZ];
#pragma unroll
      for (int d = 0; d < D_SZ; ++d) s[d] = z[d];
#define CSWAP(a, b) { float hi = fmaxf(s[a], s[b]); float lo = fminf(s[a], s[b]); s[a] = hi; s[b] = lo; }
#pragma unroll
      for (int r = 0; r < 3; ++r) {
        CSWAP(0, 1) CSWAP(2, 3) CSWAP(4, 5)
        CSWAP(1, 2) CSWAP(3, 4)
      }
#undef CSWAP
      float cs[D_SZ];
      cs[0] = s[0];
#pragma unroll
      for (int k = 1; k < D_SZ; ++k) cs[k] = cs[k - 1] + s[k];
      int kz = 0;
#pragma unroll
      for (int k = 0; k < D_SZ; ++k)
        kz += (1.0f + (float)(k + 1) * s[k] > cs[k]) ? 1 : 0;
      const float tau = (cs[kz - 1] - 1.0f) / (float)kz;
#pragma unroll
      for (int d = 0; d < D_SZ; ++d)
        selS[(j * 6 + d) * SEL_P + t] = (bf16_t)fmaxf(z[d] - tau, 0.0f);
    }
  }
  __syncthreads();

  // ---- Phase A: GEMM 48 k' x 64 b (waves 0-2); epilogue -> fv (tl values)
  if (wave < 3) {
    f32x4 acc[4];
#pragma unroll
    for (int s = 0; s < 4; ++s) acc[s] = (f32x4){0.f, 0.f, 0.f, 0.f};
    const bf16_t* arow = selS + (wave * 16 + lm) * SEL_P + q * 8;
#pragma unroll
    for (int kk = 0; kk < I_SZ; kk += 32) {
      const bf16x8 a = *(const bf16x8*)(arow + kk);
#pragma unroll
      for (int s = 0; s < 4; ++s) {
        const float* xr = x + (size_t)(btile * 64 + s * 16 + lm) * I_SZ + kk + q * 8;
        const float4 x0 = *(const float4*)(xr);
        const float4 x1 = *(const float4*)(xr + 4);
        bf16x8 bv;
        bv[0] = (bf16_t)x0.x; bv[1] = (bf16_t)x0.y; bv[2] = (bf16_t)x0.z; bv[3] = (bf16_t)x0.w;
        bv[4] = (bf16_t)x1.x; bv[5] = (bf16_t)x1.y; bv[6] = (bf16_t)x1.z; bv[7] = (bf16_t)x1.w;
        acc[s] = __builtin_amdgcn_mfma_f32_16x16x32_bf16(a, bv, acc[s], 0, 0, 0);
      }
    }
    float thv[4], ev[4];
#pragma unroll
    for (int r = 0; r < 4; ++r) {
      const int kp = ns * 48 + wave * 16 + q * 4 + r;
      thv[r] = th[kp]; ev[r] = __expf(-lt[kp]);
    }
    // C/D: row(k'_loc within 16) = q*4+r, col(b_loc within 16) = lm
#pragma unroll
    for (int s = 0; s < 4; ++s)
#pragma unroll
      for (int r = 0; r < 4; ++r)
        fv[wave * 16 + q * 4 + r][s * 16 + lm] = (acc[s][r] - thv[r]) * ev[r];
  }
  __syncthreads();

  // ---- Phase B: tree eval; wave handles b_loc in [wave*16, +16)
  f32x4 acc = (f32x4){0.f, 0.f, 0.f, 0.f};
  const int bloc = wave * 16 + lm;

#pragma unroll
  for (int j = 0; j < 8; ++j) {
    const int n = ns * 8 + j;
    // B-frags: resp f32 -> bf16 (c chunks q*8 and 32+q*8)
    const float* rb = resp + (size_t)n * (U_SZ * C_SZ) + lm * C_SZ + q * 8;
    const float4 r0 = *(const float4*)(rb);
    const float4 r1 = *(const float4*)(rb + 4);
    const float4 r2 = *(const float4*)(rb + 32);
    const float4 r3 = *(const float4*)(rb + 36);
    bf16x8 bv0, bv1;
    bv0[0] = (bf16_t)r0.x; bv0[1] = (bf16_t)r0.y; bv0[2] = (bf16_t)r0.z; bv0[3] = (bf16_t)r0.w;
    bv0[4] = (bf16_t)r1.x; bv0[5] = (bf16_t)r1.y; bv0[6] = (bf16_t)r1.z; bv0[7] = (bf16_t)r1.w;
    bv1[0] = (bf16_t)r2.x; bv1[1] = (bf16_t)r2.y; bv1[2] = (bf16_t)r2.z; bv1[3] = (bf16_t)r2.w;
    bv1[4] = (bf16_t)r3.x; bv1[5] = (bf16_t)r3.y; bv1[6] = (bf16_t)r3.z; bv1[7] = (bf16_t)r3.w;

    float b0v[D_SZ], b1v[D_SZ];
#pragma unroll
    for (int d = 0; d < D_SZ; ++d) {
      const float tl = fv[j * 6 + d][bloc];
      b1v[d] = fminf(fmaxf(0.5f * tl + 0.5f, 0.0f), 1.0f);  // bit = 0
      b0v[d] = fminf(fmaxf(0.5f - 0.5f * tl, 0.0f), 1.0f);  // bit = 1
    }
    float p2[2], p4[4], p8[8];
    p2[0] = b1v[0]; p2[1] = b0v[0];
#pragma unroll
    for (int i = 0; i < 4; ++i) p4[i] = p2[i & 1] * ((i & 2) ? b0v[1] : b1v[1]);
#pragma unroll
    for (int i = 0; i < 8; ++i) p8[i] = p4[i & 3] * ((i & 4) ? b0v[2] : b1v[2]);
    const float f3 = (q & 1) ? b0v[3] : b1v[3];
    const float f4 = (q & 2) ? b0v[4] : b1v[4];
    const float fq = f3 * f4;
    const float g0 = fq * b1v[5];   // chunk 0: bit5 = 0
    const float g1 = fq * b0v[5];   // chunk 1: bit5 = 1

    bf16x8 a0, a1;
#pragma unroll
    for (int jj = 0; jj < 8; ++jj) {
      a0[jj] = (bf16_t)(p8[jj] * g0);
      a1[jj] = (bf16_t)(p8[jj] * g1);
    }
    acc = __builtin_amdgcn_mfma_f32_16x16x32_bf16(a0, bv0, acc, 0, 0, 0);
    acc = __builtin_amdgcn_mfma_f32_16x16x32_bf16(a1, bv1, acc, 0, 0, 0);
  }

  // C/D: col(u) = lm, row(b within 16) = q*4 + r
#pragma unroll
  for (int r = 0; r < 4; ++r)
    part[(size_t)ns * (B_SZ * U_SZ) +
         (size_t)(btile * 64 + wave * 16 + q * 4 + r) * U_SZ + lm] = acc[r];
}

// ---------------------------------------------------------------------------
// Reduce: out = sum over 64 n-splits. 256 blocks; block = 64 outputs x
// 4 ns-groups of 16, LDS combine.
// ---------------------------------------------------------------------------
__global__ __launch_bounds__(256) void reduce_k(
    const float* __restrict__ part, float* __restrict__ out) {
  __shared__ float red[4][64];
  const int t = threadIdx.x;
  const int o = blockIdx.x * 64 + (t & 63);
  const int g = t >> 6;
  float s = 0.0f;
#pragma unroll
  for (int k = 0; k < 16; ++k)
    s += part[(size_t)(g * 16 + k) * (B_SZ * U_SZ) + o];
  red[g][t & 63] = s;
  __syncthreads();
  if (t < 64)
    out[blockIdx.x * 64 + t] = red[0][t] + red[1][t] + red[2][t] + red[3][t];
}

// ---------------------------------------------------------------------------
extern "C" void kernel_launch(void* const* d_in, const int* in_sizes, int n_in,
                              void* d_out, int out_size, void* d_ws, size_t ws_size,
                              hipStream_t stream) {
  const float* x    = (const float*)d_in[0];
  const float* fsl  = (const float*)d_in[1];
  const float* th   = (const float*)d_in[2];
  const float* lt   = (const float*)d_in[3];
  const float* resp = (const float*)d_in[4];
  float* out = (float*)d_out;

  float* part = (float*)d_ws;   // [64][16384] = 4 MB (only ws use)

  // 1) fused sparsemax + GEMM + tree eval -> partials (1024 blocks)
  fused_k<<<16 * NSPLIT, 256, 0, stream>>>(x, fsl, th, lt, resp, part);

  // 2) reduce partials -> out (256 blocks)
  reduce_k<<<(B_SZ * U_SZ) / 64, 256, 0, stream>>>(part, out);
}

// Round 8
// 108.158 us; speedup vs baseline: 3.1217x; 1.0130x over previous
//
#include <hip/hip_runtime.h>
#include <hip/hip_bf16.h>

// Problem constants (ODST forward):
//   x    [B=1024, I=256]  fsl [I=256,N=512,D=6]  th/lt [N=512,D=6]
//   resp [N=512, U=16, C=64]   out [B=1024, U=16]
#define B_SZ 1024
#define I_SZ 256
#define N_SZ 512
#define D_SZ 6
#define U_SZ 16
#define C_SZ 64
#define NSPLIT 64            // 8 n (48 k' rows) per fused block

typedef __bf16 bf16_t;
typedef bf16_t bf16x8 __attribute__((ext_vector_type(8)));
typedef float  f32x4  __attribute__((ext_vector_type(4)));

// ---------------------------------------------------------------------------
// Kernel 0: sparsemax over D=6 -> selT[k'=n*6+d][i] bf16 (MFMA A-layout).
// Block = 16 i x 16 n tile; coalesced fsl reads (16 consecutive n = 384 B
// rows per i). R6's in-fused sparsemax read fsl at 12 KB lane stride — 64
// lines per load instruction — and cost ~25 us; this layout is the fix.
// ---------------------------------------------------------------------------
__global__ __launch_bounds__(256) void prep_k(
    const float* __restrict__ fsl, bf16_t* __restrict__ selT) {
  __shared__ float sT[96][17];
  const int t = threadIdx.x;
  const int i_loc = t >> 4, n_loc = t & 15;
  const int n0 = (blockIdx.x & 31) * 16, i0 = (blockIdx.x >> 5) * 16;

  const float* z = fsl + ((size_t)(i0 + i_loc) * N_SZ + (n0 + n_loc)) * D_SZ;
  float v[D_SZ], s[D_SZ];
#pragma unroll
  for (int d = 0; d < D_SZ; ++d) { v[d] = z[d]; s[d] = v[d]; }

#define CSWAP(a, b) { float hi = fmaxf(s[a], s[b]); float lo = fminf(s[a], s[b]); s[a] = hi; s[b] = lo; }
#pragma unroll
  for (int r = 0; r < 3; ++r) {
    CSWAP(0, 1) CSWAP(2, 3) CSWAP(4, 5)
    CSWAP(1, 2) CSWAP(3, 4)
  }
#undef CSWAP

  float cs[D_SZ];
  cs[0] = s[0];
#pragma unroll
  for (int j = 1; j < D_SZ; ++j) cs[j] = cs[j - 1] + s[j];
  int kz = 0;
#pragma unroll
  for (int j = 0; j < D_SZ; ++j)
    kz += (1.0f + (float)(j + 1) * s[j] > cs[j]) ? 1 : 0;
  const float tau = (cs[kz - 1] - 1.0f) / (float)kz;

#pragma unroll
  for (int d = 0; d < D_SZ; ++d)
    sT[n_loc * 6 + d][i_loc] = fmaxf(v[d] - tau, 0.0f);
  __syncthreads();

  if (t < 192) {
    const int row = t >> 1, half = t & 1;
    bf16x8 o;
#pragma unroll
    for (int jj = 0; jj < 8; ++jj) o[jj] = (bf16_t)sT[row][half * 8 + jj];
    *(bf16x8*)(selT + (size_t)(n0 * 6 + row) * I_SZ + i0 + half * 8) = o;
  }
}

// ---------------------------------------------------------------------------
// Kernel 1 (fused GEMM + tree): block (btile, ns) owns b in [btile*64,+64),
// n in [ns*8,+8) = 48 k' rows. LDS = fv tile only (13 KB -> no occupancy
// squeeze; R6's 38.4 KB capped 4 blocks/CU).
//  Phase A: 48k' x 64b MFMA GEMM. A-frags: 16B global loads from selT;
//    B-frags: x f32 direct + in-register cvt (no xb prep). Epilogue folds
//    th / exp(-lt) -> LDS fv = tl values.
//  Phase B: tree eval: bins from fv (broadcast LDS reads), per-lane
//    leaf-weight A-frags (c-bits: jj=0-2 frag elem, q=3-4 lane quad,
//    chunk=5), resp f32+cvt B-frags, 2 MFMA per n -> part[ns][b][u].
// ---------------------------------------------------------------------------
__global__ __launch_bounds__(256, 4) void fused_k(
    const bf16_t* __restrict__ selT,  // [3072][256]
    const float* __restrict__ x,      // [1024][256]
    const float* __restrict__ th,     // [512][6]
    const float* __restrict__ lt,     // [512][6]
    const float* __restrict__ resp,   // [512][16][64]
    float* __restrict__ part) {       // [64 ns][1024 b][16 u]
  __shared__ float fv[48][68];        // [k'_loc][b_loc], pad 68
  const int t = threadIdx.x;
  const int lane = t & 63, wave = t >> 6;
  const int lm = lane & 15, q = lane >> 4;
  const int btile = blockIdx.x & 15, ns = blockIdx.x >> 4;

  // ---- Phase A: GEMM 48 k' x 64 b (waves 0-2); epilogue -> fv (tl values)
  if (wave < 3) {
    f32x4 acc[4];
#pragma unroll
    for (int s = 0; s < 4; ++s) acc[s] = (f32x4){0.f, 0.f, 0.f, 0.f};
    const bf16_t* arow = selT + (size_t)(ns * 48 + wave * 16 + lm) * I_SZ + q * 8;
#pragma unroll
    for (int kk = 0; kk < I_SZ; kk += 32) {
      const bf16x8 a = *(const bf16x8*)(arow + kk);
#pragma unroll
      for (int s = 0; s < 4; ++s) {
        const float* xr = x + (size_t)(btile * 64 + s * 16 + lm) * I_SZ + kk + q * 8;
        const float4 x0 = *(const float4*)(xr);
        const float4 x1 = *(const float4*)(xr + 4);
        bf16x8 bv;
        bv[0] = (bf16_t)x0.x; bv[1] = (bf16_t)x0.y; bv[2] = (bf16_t)x0.z; bv[3] = (bf16_t)x0.w;
        bv[4] = (bf16_t)x1.x; bv[5] = (bf16_t)x1.y; bv[6] = (bf16_t)x1.z; bv[7] = (bf16_t)x1.w;
        acc[s] = __builtin_amdgcn_mfma_f32_16x16x32_bf16(a, bv, acc[s], 0, 0, 0);
      }
    }
    float thv[4], ev[4];
#pragma unroll
    for (int r = 0; r < 4; ++r) {
      const int kp = ns * 48 + wave * 16 + q * 4 + r;
      thv[r] = th[kp]; ev[r] = __expf(-lt[kp]);
    }
    // C/D: row(k'_loc within 16) = q*4+r, col(b_loc within 16) = lm
#pragma unroll
    for (int s = 0; s < 4; ++s)
#pragma unroll
      for (int r = 0; r < 4; ++r)
        fv[wave * 16 + q * 4 + r][s * 16 + lm] = (acc[s][r] - thv[r]) * ev[r];
  }
  __syncthreads();

  // ---- Phase B: tree eval; wave handles b_loc in [wave*16, +16)
  f32x4 acc = (f32x4){0.f, 0.f, 0.f, 0.f};
  const int bloc = wave * 16 + lm;

#pragma unroll
  for (int j = 0; j < 8; ++j) {
    const int n = ns * 8 + j;
    // B-frags: resp f32 -> bf16 (c chunks q*8 and 32+q*8); dense 4 KB per n
    const float* rb = resp + (size_t)n * (U_SZ * C_SZ) + lm * C_SZ + q * 8;
    const float4 r0 = *(const float4*)(rb);
    const float4 r1 = *(const float4*)(rb + 4);
    const float4 r2 = *(const float4*)(rb + 32);
    const float4 r3 = *(const float4*)(rb + 36);
    bf16x8 bv0, bv1;
    bv0[0] = (bf16_t)r0.x; bv0[1] = (bf16_t)r0.y; bv0[2] = (bf16_t)r0.z; bv0[3] = (bf16_t)r0.w;
    bv0[4] = (bf16_t)r1.x; bv0[5] = (bf16_t)r1.y; bv0[6] = (bf16_t)r1.z; bv0[7] = (bf16_t)r1.w;
    bv1[0] = (bf16_t)r2.x; bv1[1] = (bf16_t)r2.y; bv1[2] = (bf16_t)r2.z; bv1[3] = (bf16_t)r2.w;
    bv1[4] = (bf16_t)r3.x; bv1[5] = (bf16_t)r3.y; bv1[6] = (bf16_t)r3.z; bv1[7] = (bf16_t)r3.w;

    float b0v[D_SZ], b1v[D_SZ];
#pragma unroll
    for (int d = 0; d < D_SZ; ++d) {
      const float tl = fv[j * 6 + d][bloc];
      b1v[d] = fminf(fmaxf(0.5f * tl + 0.5f, 0.0f), 1.0f);  // bit = 0
      b0v[d] = fminf(fmaxf(0.5f - 0.5f * tl, 0.0f), 1.0f);  // bit = 1
    }
    float p2[2], p4[4], p8[8];
    p2[0] = b1v[0]; p2[1] = b0v[0];
#pragma unroll
    for (int i = 0; i < 4; ++i) p4[i] = p2[i & 1] * ((i & 2) ? b0v[1] : b1v[1]);
#pragma unroll
    for (int i = 0; i < 8; ++i) p8[i] = p4[i & 3] * ((i & 4) ? b0v[2] : b1v[2]);
    const float f3 = (q & 1) ? b0v[3] : b1v[3];
    const float f4 = (q & 2) ? b0v[4] : b1v[4];
    const float fq = f3 * f4;
    const float g0 = fq * b1v[5];   // chunk 0: bit5 = 0
    const float g1 = fq * b0v[5];   // chunk 1: bit5 = 1

    bf16x8 a0, a1;
#pragma unroll
    for (int jj = 0; jj < 8; ++jj) {
      a0[jj] = (bf16_t)(p8[jj] * g0);
      a1[jj] = (bf16_t)(p8[jj] * g1);
    }
    acc = __builtin_amdgcn_mfma_f32_16x16x32_bf16(a0, bv0, acc, 0, 0, 0);
    acc = __builtin_amdgcn_mfma_f32_16x16x32_bf16(a1, bv1, acc, 0, 0, 0);
  }

  // C/D: col(u) = lm, row(b within 16) = q*4 + r
#pragma unroll
  for (int r = 0; r < 4; ++r)
    part[(size_t)ns * (B_SZ * U_SZ) +
         (size_t)(btile * 64 + wave * 16 + q * 4 + r) * U_SZ + lm] = acc[r];
}

// ---------------------------------------------------------------------------
// Kernel 2: out = sum over 64 n-splits. 256 blocks; block = 64 outputs x
// 4 ns-groups of 16, LDS combine.
// ---------------------------------------------------------------------------
__global__ __launch_bounds__(256) void reduce_k(
    const float* __restrict__ part, float* __restrict__ out) {
  __shared__ float red[4][64];
  const int t = threadIdx.x;
  const int o = blockIdx.x * 64 + (t & 63);
  const int g = t >> 6;
  float s = 0.0f;
#pragma unroll
  for (int k = 0; k < 16; ++k)
    s += part[(size_t)(g * 16 + k) * (B_SZ * U_SZ) + o];
  red[g][t & 63] = s;
  __syncthreads();
  if (t < 64)
    out[blockIdx.x * 64 + t] = red[0][t] + red[1][t] + red[2][t] + red[3][t];
}

// ---------------------------------------------------------------------------
extern "C" void kernel_launch(void* const* d_in, const int* in_sizes, int n_in,
                              void* d_out, int out_size, void* d_ws, size_t ws_size,
                              hipStream_t stream) {
  const float* x    = (const float*)d_in[0];
  const float* fsl  = (const float*)d_in[1];
  const float* th   = (const float*)d_in[2];
  const float* lt   = (const float*)d_in[3];
  const float* resp = (const float*)d_in[4];
  float* out = (float*)d_out;

  char* w = (char*)d_ws;
  bf16_t* selT = (bf16_t*)(w);              // 1572864 B  [3072][256]
  float*  part = (float*)(w + 1572864);     // 4194304 B  [64][16384]

  // 0) sparsemax -> selT (bf16, A-operand layout)
  prep_k<<<512, 256, 0, stream>>>(fsl, selT);

  // 1) fused GEMM + tree eval -> partials (1024 blocks)
  fused_k<<<16 * NSPLIT, 256, 0, stream>>>(selT, x, th, lt, resp, part);

  // 2) reduce partials -> out (256 blocks)
  reduce_k<<<(B_SZ * U_SZ) / 64, 256, 0, stream>>>(part, out);
}

// Round 10
// 80.119 us; speedup vs baseline: 4.2142x; 1.3500x over previous
//
#include <hip/hip_runtime.h>
#include <hip/hip_bf16.h>

// Problem constants (ODST forward):
//   x    [B=1024, I=256]  fsl [I=256,N=512,D=6]  th/lt [N=512,D=6]
//   resp [N=512, U=16, C=64]   out [B=1024, U=16]
#define B_SZ 1024
#define I_SZ 256
#define N_SZ 512
#define D_SZ 6
#define U_SZ 16
#define C_SZ 64
#define NSPLIT 64            // 8 n (48 k' rows) per fused block

typedef __bf16 bf16_t;
typedef bf16_t bf16x8 __attribute__((ext_vector_type(8)));
typedef float  f32x4  __attribute__((ext_vector_type(4)));

// Fragment-order ("packed") operand layouts. A 16x16x32 MFMA operand frag is
// 64 lanes x 16 B; packed offset = (frag_linear*64 + lane)*8 bf16 so the wave's
// load is one contiguous 1-KB burst. R7's direct loads had each lane on its own
// row (64 cache lines PER INSTRUCTION) — TA address-serialization made fused_k
// 42 us with every pipe <12% busy.
//   selF:  frag (g=k'/16, kk) lane(lm,q) = sel[i=kk*32+q*8+jj][k'=g*16+lm]
//   xbF:   frag (gb=b/16, kk) lane(lm,q) = x[b=gb*16+lm][i=kk*32+q*8+jj]
//   respF: frag (n, chunk)    lane(lm,q) = resp[n][u=lm][c=chunk*32+q*8+jj]

// ---------------------------------------------------------------------------
// prep_pack: one dispatch, three block ranges (branch is block-uniform).
//   bid [0,512)   : sparsemax (16i x 16n tile, coalesced fsl) -> selF
//   bid [512,576) : x 16-row tile -> LDS -> xbF
//   bid [576,704) : resp 4-n tile -> LDS -> respF
// ---------------------------------------------------------------------------
__global__ __launch_bounds__(256) void prep_pack(
    const float* __restrict__ fsl, const float* __restrict__ x,
    const float* __restrict__ resp,
    bf16_t* __restrict__ selF, bf16_t* __restrict__ xbF,
    bf16_t* __restrict__ respF) {
  __shared__ float smem[4160];   // 16640 B, reused per branch
  const int bid = blockIdx.x, t = threadIdx.x;

  if (bid < 512) {
    // ---- sparsemax: nb = n-tile (16 n), ib = i-tile (16 i)
    float (*sT)[17] = (float(*)[17])smem;          // [96][17]
    const int nb = bid & 31, ib = bid >> 5;
    const int i_loc = t >> 4, n_loc = t & 15;
    const int n0 = nb * 16, i0 = ib * 16;

    const float* z = fsl + ((size_t)(i0 + i_loc) * N_SZ + (n0 + n_loc)) * D_SZ;
    float v[D_SZ], s[D_SZ];
#pragma unroll
    for (int d = 0; d < D_SZ; ++d) { v[d] = z[d]; s[d] = v[d]; }
#define CSWAP(a, b) { float hi = fmaxf(s[a], s[b]); float lo = fminf(s[a], s[b]); s[a] = hi; s[b] = lo; }
#pragma unroll
    for (int r = 0; r < 3; ++r) {
      CSWAP(0, 1) CSWAP(2, 3) CSWAP(4, 5)
      CSWAP(1, 2) CSWAP(3, 4)
    }
#undef CSWAP
    float cs[D_SZ];
    cs[0] = s[0];
#pragma unroll
    for (int j = 1; j < D_SZ; ++j) cs[j] = cs[j - 1] + s[j];
    int kz = 0;
#pragma unroll
    for (int j = 0; j < D_SZ; ++j)
      kz += (1.0f + (float)(j + 1) * s[j] > cs[j]) ? 1 : 0;
    const float tau = (cs[kz - 1] - 1.0f) / (float)kz;
#pragma unroll
    for (int d = 0; d < D_SZ; ++d)
      sT[n_loc * 6 + d][i_loc] = fmaxf(v[d] - tau, 0.0f);
    __syncthreads();

    if (t < 192) {
      const int r = t >> 1, h = t & 1;             // r: 96 k' rows, h: i half
      const int g  = 6 * nb + (r >> 4), lm = r & 15;
      const int kk = ib >> 1, q = (ib & 1) * 2 + h;
      bf16x8 o;
#pragma unroll
      for (int jj = 0; jj < 8; ++jj) o[jj] = (bf16_t)sT[r][h * 8 + jj];
      *(bf16x8*)(selF + ((size_t)(g * 8 + kk) * 64 + q * 16 + lm) * 8) = o;
    }
  } else if (bid < 576) {
    // ---- x pack: 16 b rows -> 8 frags x 64 lanes = 512 writes (2 rounds)
    float (*xs)[257] = (float(*)[257])smem;        // [16][257]
    const int gb = bid - 512;
#pragma unroll
    for (int c = 0; c < 4; ++c) {
      const int e = c * 256 + t;                   // float4 index, 64 per row
      const int row = e >> 6, col = (e & 63) * 4;
      const float4 v = *(const float4*)(x + (size_t)(gb * 16 + row) * I_SZ + col);
      xs[row][col] = v.x; xs[row][col + 1] = v.y;
      xs[row][col + 2] = v.z; xs[row][col + 3] = v.w;
    }
    __syncthreads();
#pragma unroll
    for (int h = 0; h < 2; ++h) {
      const int fid = h * 256 + t;                 // 0..511
      const int kk = fid >> 6, lane = fid & 63;
      const int lm = lane & 15, q = lane >> 4;
      bf16x8 o;
#pragma unroll
      for (int jj = 0; jj < 8; ++jj) o[jj] = (bf16_t)xs[lm][kk * 32 + q * 8 + jj];
      *(bf16x8*)(xbF + ((size_t)(gb * 8 + kk) * 64 + lane) * 8) = o;
    }
  } else {
    // ---- resp pack: 4 n rows -> 4n x 2chunk x 64lane = 512 writes.
    // R8 BUG: loop ran h<4 -> n_loc up to 7, OOB LDS reads raced into the
    // next block's respF region (absmax 61). Correct count is 2 rounds.
    float (*rs)[16][65] = (float(*)[16][65])smem;  // [4][16][65]
    const int n0 = (bid - 576) * 4;
#pragma unroll
    for (int c = 0; c < 4; ++c) {
      const int e = c * 256 + t;                   // float4 index, 256 per n
      const int n_loc = e >> 8, idx = (e & 255) * 4;
      const int u = idx >> 6, cc = idx & 63;
      const float4 v = *(const float4*)(resp + (size_t)(n0 + n_loc) * 1024 + idx);
      rs[n_loc][u][cc] = v.x; rs[n_loc][u][cc + 1] = v.y;
      rs[n_loc][u][cc + 2] = v.z; rs[n_loc][u][cc + 3] = v.w;
    }
    __syncthreads();
#pragma unroll
    for (int h = 0; h < 2; ++h) {
      const int fid = h * 256 + t;                 // 0..511
      const int n_loc = fid >> 7, chunk = (fid >> 6) & 1, lane = fid & 63;
      const int lm = lane & 15, q = lane >> 4;
      bf16x8 o;
#pragma unroll
      for (int jj = 0; jj < 8; ++jj)
        o[jj] = (bf16_t)rs[n_loc][lm][chunk * 32 + q * 8 + jj];
      *(bf16x8*)(respF + ((size_t)((n0 + n_loc) * 2 + chunk) * 64 + lane) * 8) = o;
    }
  }
}

// ---------------------------------------------------------------------------
// fused_k: block (btile, ns) owns b in [btile*64,+64), n in [ns*8,+8).
//  Phase A (waves 0-2): 48k' x 64b MFMA GEMM; A/B frags are single coalesced
//    1-KB packed loads. Epilogue folds th/exp(-lt) -> LDS fv (= tl values).
//  Phase B (all 4 waves): bins from fv, per-lane leaf-weight A-frags
//    (c-bits: jj=0-2 frag elem, q=3-4 lane quad, chunk=5), packed respF
//    B-frags, 2 MFMA per n -> part[ns][b][u].
// ---------------------------------------------------------------------------
__global__ __launch_bounds__(256, 4) void fused_k(
    const bf16_t* __restrict__ selF,  // packed [192][8][64][8]
    const bf16_t* __restrict__ xbF,   // packed [64][8][64][8]
    const float* __restrict__ th,     // [512][6]
    const float* __restrict__ lt,     // [512][6]
    const bf16_t* __restrict__ respF, // packed [512][2][64][8]
    float* __restrict__ part) {       // [64 ns][1024 b][16 u]
  __shared__ float fv[48][68];        // [k'_loc][b_loc], pad 68
  const int t = threadIdx.x;
  const int lane = t & 63, wave = t >> 6;
  const int lm = lane & 15, q = lane >> 4;
  const int btile = blockIdx.x & 15, ns = blockIdx.x >> 4;

  // ---- Phase A: GEMM 48 k' x 64 b (waves 0-2)
  if (wave < 3) {
    f32x4 acc[4];
#pragma unroll
    for (int s = 0; s < 4; ++s) acc[s] = (f32x4){0.f, 0.f, 0.f, 0.f};
    const int g = ns * 3 + wave;
    const bf16_t* aF = selF + ((size_t)g * 8 * 64 + lane) * 8;
    const bf16_t* bF = xbF + ((size_t)btile * 4 * 8 * 64 + lane) * 8;
#pragma unroll
    for (int kk = 0; kk < 8; ++kk) {
      const bf16x8 a = *(const bf16x8*)(aF + (size_t)kk * 64 * 8);
#pragma unroll
      for (int s = 0; s < 4; ++s) {
        const bf16x8 bv = *(const bf16x8*)(bF + (size_t)(s * 8 + kk) * 64 * 8);
        acc[s] = __builtin_amdgcn_mfma_f32_16x16x32_bf16(a, bv, acc[s], 0, 0, 0);
      }
    }
    float thv[4], ev[4];
#pragma unroll
    for (int r = 0; r < 4; ++r) {
      const int kp = ns * 48 + wave * 16 + q * 4 + r;
      thv[r] = th[kp]; ev[r] = __expf(-lt[kp]);
    }
    // C/D: row(k'_loc within 16) = q*4+r, col(b_loc within 16) = lm
#pragma unroll
    for (int s = 0; s < 4; ++s)
#pragma unroll
      for (int r = 0; r < 4; ++r)
        fv[wave * 16 + q * 4 + r][s * 16 + lm] = (acc[s][r] - thv[r]) * ev[r];
  }
  __syncthreads();

  // ---- Phase B: tree eval; wave handles b_loc in [wave*16, +16)
  f32x4 acc = (f32x4){0.f, 0.f, 0.f, 0.f};
  const int bloc = wave * 16 + lm;

#pragma unroll
  for (int j = 0; j < 8; ++j) {
    const int n = ns * 8 + j;
    const bf16_t* rF = respF + ((size_t)n * 2 * 64 + lane) * 8;
    const bf16x8 bv0 = *(const bf16x8*)(rF);
    const bf16x8 bv1 = *(const bf16x8*)(rF + 64 * 8);

    float b0v[D_SZ], b1v[D_SZ];
#pragma unroll
    for (int d = 0; d < D_SZ; ++d) {
      const float tl = fv[j * 6 + d][bloc];
      b1v[d] = fminf(fmaxf(0.5f * tl + 0.5f, 0.0f), 1.0f);  // bit = 0
      b0v[d] = fminf(fmaxf(0.5f - 0.5f * tl, 0.0f), 1.0f);  // bit = 1
    }
    float p2[2], p4[4], p8[8];
    p2[0] = b1v[0]; p2[1] = b0v[0];
#pragma unroll
    for (int i = 0; i < 4; ++i) p4[i] = p2[i & 1] * ((i & 2) ? b0v[1] : b1v[1]);
#pragma unroll
    for (int i = 0; i < 8; ++i) p8[i] = p4[i & 3] * ((i & 4) ? b0v[2] : b1v[2]);
    const float f3 = (q & 1) ? b0v[3] : b1v[3];
    const float f4 = (q & 2) ? b0v[4] : b1v[4];
    const float fq = f3 * f4;
    const float g0 = fq * b1v[5];   // chunk 0: bit5 = 0
    const float g1 = fq * b0v[5];   // chunk 1: bit5 = 1

    bf16x8 a0, a1;
#pragma unroll
    for (int jj = 0; jj < 8; ++jj) {
      a0[jj] = (bf16_t)(p8[jj] * g0);
      a1[jj] = (bf16_t)(p8[jj] * g1);
    }
    acc = __builtin_amdgcn_mfma_f32_16x16x32_bf16(a0, bv0, acc, 0, 0, 0);
    acc = __builtin_amdgcn_mfma_f32_16x16x32_bf16(a1, bv1, acc, 0, 0, 0);
  }

  // C/D: col(u) = lm, row(b within 16) = q*4 + r
#pragma unroll
  for (int r = 0; r < 4; ++r)
    part[(size_t)ns * (B_SZ * U_SZ) +
         (size_t)(btile * 64 + wave * 16 + q * 4 + r) * U_SZ + lm] = acc[r];
}

// ---------------------------------------------------------------------------
// reduce_k: out = sum over 64 n-splits. 256 blocks; 64 outputs x 4 ns-groups.
// ---------------------------------------------------------------------------
__global__ __launch_bounds__(256) void reduce_k(
    const float* __restrict__ part, float* __restrict__ out) {
  __shared__ float red[4][64];
  const int t = threadIdx.x;
  const int o = blockIdx.x * 64 + (t & 63);
  const int g = t >> 6;
  float s = 0.0f;
#pragma unroll
  for (int k = 0; k < 16; ++k)
    s += part[(size_t)(g * 16 + k) * (B_SZ * U_SZ) + o];
  red[g][t & 63] = s;
  __syncthreads();
  if (t < 64)
    out[blockIdx.x * 64 + t] = red[0][t] + red[1][t] + red[2][t] + red[3][t];
}

// ---------------------------------------------------------------------------
extern "C" void kernel_launch(void* const* d_in, const int* in_sizes, int n_in,
                              void* d_out, int out_size, void* d_ws, size_t ws_size,
                              hipStream_t stream) {
  const float* x    = (const float*)d_in[0];
  const float* fsl  = (const float*)d_in[1];
  const float* th   = (const float*)d_in[2];
  const float* lt   = (const float*)d_in[3];
  const float* resp = (const float*)d_in[4];
  float* out = (float*)d_out;

  char* w = (char*)d_ws;
  bf16_t* selF  = (bf16_t*)(w);                 // 1572864 B  packed sel
  bf16_t* xbF   = (bf16_t*)(w + 1572864);       //  524288 B  packed x
  bf16_t* respF = (bf16_t*)(w + 2097152);       // 1048576 B  packed resp
  float*  part  = (float*)(w + 3145728);        // 4194304 B  [64][16384]

  // 0) pack all MFMA operands (sparsemax + casts + fragment permutation)
  prep_pack<<<704, 256, 0, stream>>>(fsl, x, resp, selF, xbF, respF);

  // 1) fused GEMM + tree eval -> partials (1024 blocks)
  fused_k<<<16 * NSPLIT, 256, 0, stream>>>(selF, xbF, th, lt, respF, part);

  // 2) reduce partials -> out (256 blocks)
  reduce_k<<<(B_SZ * U_SZ) / 64, 256, 0, stream>>>(part, out);
}

// Round 11
// 77.834 us; speedup vs baseline: 4.3379x; 1.0294x over previous
//
#include <hip/hip_runtime.h>
#include <hip/hip_bf16.h>

// Problem constants (ODST forward):
//   x    [B=1024, I=256]  fsl [I=256,N=512,D=6]  th/lt [N=512,D=6]
//   resp [N=512, U=16, C=64]   out [B=1024, U=16]
#define B_SZ 1024
#define I_SZ 256
#define N_SZ 512
#define D_SZ 6
#define U_SZ 16
#define C_SZ 64
#define NSPLIT 64            // 8 n (48 k' rows) per fused block

typedef __bf16 bf16_t;
typedef bf16_t bf16x8 __attribute__((ext_vector_type(8)));
typedef float  f32x4  __attribute__((ext_vector_type(4)));

// Fragment-order ("packed") operand layouts (verified R9). A 16x16x32 MFMA
// operand frag is 64 lanes x 16 B; packed offset = (frag_linear*64 + lane)*16 B
// so a wave's frag load is one contiguous 1-KB burst. (R7's direct loads put
// each lane on its own row -> 64 cache lines PER INSTRUCTION -> TA
// serialization; fused_k was 42 us with all pipes <12% busy.)
//   selF:  frag (g=k'/16, kk) lane(lm,q) = sel[i=kk*32+q*8+jj][k'=g*16+lm]
//   xbF:   frag (gb=b/16, kk) lane(lm,q) = x[b=gb*16+lm][i=kk*32+q*8+jj]
//   respF: frag (n, chunk)    lane(lm,q) = resp[n][u=lm][c=chunk*32+q*8+jj]

// ---------------------------------------------------------------------------
// prep_pack: one dispatch, four block ranges (branch is block-uniform).
//   bid [0,512)   : sparsemax (16i x 16n tile, coalesced fsl) -> selF
//   bid [512,576) : x 16-row tile -> LDS -> xbF
//   bid [576,704) : resp 4-n tile -> LDS -> respF
//   bid [704,720) : zero d_out (harness poisons it to 0xAA; fused atomicAdds)
// ---------------------------------------------------------------------------
__global__ __launch_bounds__(256) void prep_pack(
    const float* __restrict__ fsl, const float* __restrict__ x,
    const float* __restrict__ resp,
    bf16_t* __restrict__ selF, bf16_t* __restrict__ xbF,
    bf16_t* __restrict__ respF, float* __restrict__ out) {
  __shared__ float smem[4160];   // 16640 B, reused per branch
  const int bid = blockIdx.x, t = threadIdx.x;

  if (bid < 512) {
    // ---- sparsemax: nb = n-tile (16 n), ib = i-tile (16 i)
    float (*sT)[17] = (float(*)[17])smem;          // [96][17]
    const int nb = bid & 31, ib = bid >> 5;
    const int i_loc = t >> 4, n_loc = t & 15;
    const int n0 = nb * 16, i0 = ib * 16;

    const float* z = fsl + ((size_t)(i0 + i_loc) * N_SZ + (n0 + n_loc)) * D_SZ;
    float v[D_SZ], s[D_SZ];
#pragma unroll
    for (int d = 0; d < D_SZ; ++d) { v[d] = z[d]; s[d] = v[d]; }
#define CSWAP(a, b) { float hi = fmaxf(s[a], s[b]); float lo = fminf(s[a], s[b]); s[a] = hi; s[b] = lo; }
#pragma unroll
    for (int r = 0; r < 3; ++r) {
      CSWAP(0, 1) CSWAP(2, 3) CSWAP(4, 5)
      CSWAP(1, 2) CSWAP(3, 4)
    }
#undef CSWAP
    float cs[D_SZ];
    cs[0] = s[0];
#pragma unroll
    for (int j = 1; j < D_SZ; ++j) cs[j] = cs[j - 1] + s[j];
    int kz = 0;
#pragma unroll
    for (int j = 0; j < D_SZ; ++j)
      kz += (1.0f + (float)(j + 1) * s[j] > cs[j]) ? 1 : 0;
    const float tau = (cs[kz - 1] - 1.0f) / (float)kz;
#pragma unroll
    for (int d = 0; d < D_SZ; ++d)
      sT[n_loc * 6 + d][i_loc] = fmaxf(v[d] - tau, 0.0f);
    __syncthreads();

    if (t < 192) {
      const int r = t >> 1, h = t & 1;             // r: 96 k' rows, h: i half
      const int g  = 6 * nb + (r >> 4), lm = r & 15;
      const int kk = ib >> 1, q = (ib & 1) * 2 + h;
      bf16x8 o;
#pragma unroll
      for (int jj = 0; jj < 8; ++jj) o[jj] = (bf16_t)sT[r][h * 8 + jj];
      *(bf16x8*)(selF + ((size_t)(g * 8 + kk) * 64 + q * 16 + lm) * 8) = o;
    }
  } else if (bid < 576) {
    // ---- x pack: 16 b rows -> 8 frags x 64 lanes = 512 writes (2 rounds)
    float (*xs)[257] = (float(*)[257])smem;        // [16][257]
    const int gb = bid - 512;
#pragma unroll
    for (int c = 0; c < 4; ++c) {
      const int e = c * 256 + t;                   // float4 index, 64 per row
      const int row = e >> 6, col = (e & 63) * 4;
      const float4 v = *(const float4*)(x + (size_t)(gb * 16 + row) * I_SZ + col);
      xs[row][col] = v.x; xs[row][col + 1] = v.y;
      xs[row][col + 2] = v.z; xs[row][col + 3] = v.w;
    }
    __syncthreads();
#pragma unroll
    for (int h = 0; h < 2; ++h) {
      const int fid = h * 256 + t;                 // 0..511
      const int kk = fid >> 6, lane = fid & 63;
      const int lm = lane & 15, q = lane >> 4;
      bf16x8 o;
#pragma unroll
      for (int jj = 0; jj < 8; ++jj) o[jj] = (bf16_t)xs[lm][kk * 32 + q * 8 + jj];
      *(bf16x8*)(xbF + ((size_t)(gb * 8 + kk) * 64 + lane) * 8) = o;
    }
  } else if (bid < 704) {
    // ---- resp pack: 4 n rows -> 4n x 2chunk x 64lane = 512 writes (2 rounds)
    float (*rs)[16][65] = (float(*)[16][65])smem;  // [4][16][65]
    const int n0 = (bid - 576) * 4;
#pragma unroll
    for (int c = 0; c < 4; ++c) {
      const int e = c * 256 + t;                   // float4 index, 256 per n
      const int n_loc = e >> 8, idx = (e & 255) * 4;
      const int u = idx >> 6, cc = idx & 63;
      const float4 v = *(const float4*)(resp + (size_t)(n0 + n_loc) * 1024 + idx);
      rs[n_loc][u][cc] = v.x; rs[n_loc][u][cc + 1] = v.y;
      rs[n_loc][u][cc + 2] = v.z; rs[n_loc][u][cc + 3] = v.w;
    }
    __syncthreads();
#pragma unroll
    for (int h = 0; h < 2; ++h) {
      const int fid = h * 256 + t;                 // 0..511
      const int n_loc = fid >> 7, chunk = (fid >> 6) & 1, lane = fid & 63;
      const int lm = lane & 15, q = lane >> 4;
      bf16x8 o;
#pragma unroll
      for (int jj = 0; jj < 8; ++jj)
        o[jj] = (bf16_t)rs[n_loc][lm][chunk * 32 + q * 8 + jj];
      *(bf16x8*)(respF + ((size_t)((n0 + n_loc) * 2 + chunk) * 64 + lane) * 8) = o;
    }
  } else {
    // ---- zero out[1024][16]: 16 blocks x 256 threads x 1 float4 = 16384 f32
    const int idx = ((bid - 704) * 256 + t) * 4;
    *(float4*)(out + idx) = make_float4(0.f, 0.f, 0.f, 0.f);
  }
}

// ---------------------------------------------------------------------------
// fused_k: block (btile, ns) owns b in [btile*64,+64), n in [ns*8,+8).
//  Phase A (ALL 4 waves; R10 idled wave 3): wave w = b-subtile, 3 k'-group
//    accumulators; 24 MFMA + 32 coalesced 1-KB frag loads per wave. Epilogue
//    folds th/exp(-lt) -> LDS fv (= tl values), wave w writes cols [w*16,+16).
//  Phase B: bins from fv, per-lane leaf-weight A-frags (c-bits: jj=0-2 frag
//    elem, q=3-4 lane quad, chunk=5), packed respF B-frags, 2 MFMA per n.
//  Epilogue: atomicAdd into out. C-layout => one atomic instr covers
//    4 rows x 16 u = 4 cache lines (R1's lane=b scatter hit 64 lines/instr);
//    64K line-ops total over 1024 lines — ~65x fewer than R1. Replaces the
//    part buffer (8 MB traffic) + reduce_k dispatch + one launch gap.
// ---------------------------------------------------------------------------
__global__ __launch_bounds__(256, 4) void fused_k(
    const bf16_t* __restrict__ selF,  // packed [192][8][64][8]
    const bf16_t* __restrict__ xbF,   // packed [64][8][64][8]
    const float* __restrict__ th,     // [512][6]
    const float* __restrict__ lt,     // [512][6]
    const bf16_t* __restrict__ respF, // packed [512][2][64][8]
    float* __restrict__ out) {        // [1024 b][16 u], pre-zeroed by prep
  __shared__ float fv[48][68];        // [k'_loc][b_loc], pad 68
  const int t = threadIdx.x;
  const int lane = t & 63, wave = t >> 6;
  const int lm = lane & 15, q = lane >> 4;
  const int btile = blockIdx.x & 15, ns = blockIdx.x >> 4;

  // ---- Phase A: GEMM 48 k' x 64 b; wave w = b-subtile w
  {
    f32x4 acc[3];
#pragma unroll
    for (int kg = 0; kg < 3; ++kg) acc[kg] = (f32x4){0.f, 0.f, 0.f, 0.f};
    const bf16_t* aF = selF + ((size_t)(ns * 3) * 8 * 64 + lane) * 8;
    const bf16_t* bF = xbF + ((size_t)(btile * 4 + wave) * 8 * 64 + lane) * 8;
#pragma unroll
    for (int kk = 0; kk < 8; ++kk) {
      const bf16x8 bv = *(const bf16x8*)(bF + (size_t)kk * 64 * 8);
#pragma unroll
      for (int kg = 0; kg < 3; ++kg) {
        const bf16x8 a = *(const bf16x8*)(aF + (size_t)(kg * 8 + kk) * 64 * 8);
        acc[kg] = __builtin_amdgcn_mfma_f32_16x16x32_bf16(a, bv, acc[kg], 0, 0, 0);
      }
    }
    // C/D: row(k'_loc) = kg*16 + q*4 + r, col(b_loc) = wave*16 + lm
#pragma unroll
    for (int kg = 0; kg < 3; ++kg) {
      float thv[4], ev[4];
#pragma unroll
      for (int r = 0; r < 4; ++r) {
        const int kp = ns * 48 + kg * 16 + q * 4 + r;
        thv[r] = th[kp]; ev[r] = __expf(-lt[kp]);
      }
#pragma unroll
      for (int r = 0; r < 4; ++r)
        fv[kg * 16 + q * 4 + r][wave * 16 + lm] = (acc[kg][r] - thv[r]) * ev[r];
    }
  }
  __syncthreads();

  // ---- Phase B: tree eval; wave handles b_loc in [wave*16, +16)
  f32x4 acc = (f32x4){0.f, 0.f, 0.f, 0.f};
  const int bloc = wave * 16 + lm;

#pragma unroll
  for (int j = 0; j < 8; ++j) {
    const int n = ns * 8 + j;
    const bf16_t* rF = respF + ((size_t)n * 2 * 64 + lane) * 8;
    const bf16x8 bv0 = *(const bf16x8*)(rF);
    const bf16x8 bv1 = *(const bf16x8*)(rF + 64 * 8);

    float b0v[D_SZ], b1v[D_SZ];
#pragma unroll
    for (int d = 0; d < D_SZ; ++d) {
      const float tl = fv[j * 6 + d][bloc];
      b1v[d] = fminf(fmaxf(0.5f * tl + 0.5f, 0.0f), 1.0f);  // bit = 0
      b0v[d] = fminf(fmaxf(0.5f - 0.5f * tl, 0.0f), 1.0f);  // bit = 1
    }
    float p2[2], p4[4], p8[8];
    p2[0] = b1v[0]; p2[1] = b0v[0];
#pragma unroll
    for (int i = 0; i < 4; ++i) p4[i] = p2[i & 1] * ((i & 2) ? b0v[1] : b1v[1]);
#pragma unroll
    for (int i = 0; i < 8; ++i) p8[i] = p4[i & 3] * ((i & 4) ? b0v[2] : b1v[2]);
    const float f3 = (q & 1) ? b0v[3] : b1v[3];
    const float f4 = (q & 2) ? b0v[4] : b1v[4];
    const float fq = f3 * f4;
    const float g0 = fq * b1v[5];   // chunk 0: bit5 = 0
    const float g1 = fq * b0v[5];   // chunk 1: bit5 = 1

    bf16x8 a0, a1;
#pragma unroll
    for (int jj = 0; jj < 8; ++jj) {
      a0[jj] = (bf16_t)(p8[jj] * g0);
      a1[jj] = (bf16_t)(p8[jj] * g1);
    }
    acc = __builtin_amdgcn_mfma_f32_16x16x32_bf16(a0, bv0, acc, 0, 0, 0);
    acc = __builtin_amdgcn_mfma_f32_16x16x32_bf16(a1, bv1, acc, 0, 0, 0);
  }

  // C/D: col(u) = lm, row(b within 16) = q*4 + r; accumulate over ns-blocks
  float* obase = out + (size_t)(btile * 64 + wave * 16) * U_SZ;
#pragma unroll
  for (int r = 0; r < 4; ++r)
    atomicAdd(&obase[(q * 4 + r) * U_SZ + lm], acc[r]);
}

// ---------------------------------------------------------------------------
extern "C" void kernel_launch(void* const* d_in, const int* in_sizes, int n_in,
                              void* d_out, int out_size, void* d_ws, size_t ws_size,
                              hipStream_t stream) {
  const float* x    = (const float*)d_in[0];
  const float* fsl  = (const float*)d_in[1];
  const float* th   = (const float*)d_in[2];
  const float* lt   = (const float*)d_in[3];
  const float* resp = (const float*)d_in[4];
  float* out = (float*)d_out;

  char* w = (char*)d_ws;
  bf16_t* selF  = (bf16_t*)(w);                 // 1572864 B  packed sel
  bf16_t* xbF   = (bf16_t*)(w + 1572864);       //  524288 B  packed x
  bf16_t* respF = (bf16_t*)(w + 2097152);       // 1048576 B  packed resp

  // 0) pack all MFMA operands + zero out (sparsemax + casts + permutation)
  prep_pack<<<720, 256, 0, stream>>>(fsl, x, resp, selF, xbF, respF, out);

  // 1) fused GEMM + tree eval, atomic-accumulated into out (1024 blocks)
  fused_k<<<16 * NSPLIT, 256, 0, stream>>>(selF, xbF, th, lt, respF, out);
}

// Round 12
// 77.031 us; speedup vs baseline: 4.3831x; 1.0104x over previous
//
#include <hip/hip_runtime.h>
#include <hip/hip_bf16.h>

// Problem constants (ODST forward):
//   x    [B=1024, I=256]  fsl [I=256,N=512,D=6]  th/lt [N=512,D=6]
//   resp [N=512, U=16, C=64]   out [B=1024, U=16]
#define B_SZ 1024
#define I_SZ 256
#define N_SZ 512
#define D_SZ 6
#define U_SZ 16
#define C_SZ 64
#define NSPLIT 64            // 8 n (48 k' rows) per fused block

typedef __bf16 bf16_t;
typedef bf16_t bf16x8 __attribute__((ext_vector_type(8)));
typedef float  f32x4  __attribute__((ext_vector_type(4)));

// Fragment-order ("packed") operand layouts (verified R9/R10). A 16x16x32 MFMA
// operand frag is 64 lanes x 16 B; packed offset = (frag_linear*64 + lane)*16 B
// so a wave's frag load is one contiguous 1-KB burst (R7's direct loads put
// each lane on its own row -> 64 lines/instruction -> TA serialization).
//   selF:  frag (g=k'/16, kk) lane(lm,q) = sel[i=kk*32+q*8+jj][k'=g*16+lm]
//   xbF:   frag (gb=b/16, kk) lane(lm,q) = x[b=gb*16+lm][i=kk*32+q*8+jj]
//   respF: frag (n, chunk)    lane(lm,q) = resp[n][u=lm][c=chunk*32+q*8+jj]
//   sb[kp] = (scale, bias) = (exp(-lt), -th*exp(-lt))  — tl = fv*scale + bias

// ---------------------------------------------------------------------------
// prep_pack: one dispatch, five block ranges (branch is block-uniform).
//   bid [0,512)   : sparsemax (16i x 16n tile, coalesced fsl) -> selF
//   bid [512,576) : x 16-row tile -> LDS -> xbF
//   bid [576,704) : resp 4-n tile -> LDS -> respF
//   bid [704,720) : zero d_out (harness poisons to 0xAA; fused atomicAdds)
//   bid [720,732) : sb = (exp(-lt), -th*exp(-lt))
// ---------------------------------------------------------------------------
__global__ __launch_bounds__(256) void prep_pack(
    const float* __restrict__ fsl, const float* __restrict__ x,
    const float* __restrict__ resp, const float* __restrict__ th,
    const float* __restrict__ lt,
    bf16_t* __restrict__ selF, bf16_t* __restrict__ xbF,
    bf16_t* __restrict__ respF, float2* __restrict__ sb,
    float* __restrict__ out) {
  __shared__ float smem[4160];   // 16640 B, reused per branch
  const int bid = blockIdx.x, t = threadIdx.x;

  if (bid < 512) {
    // ---- sparsemax: nb = n-tile (16 n), ib = i-tile (16 i)
    float (*sT)[17] = (float(*)[17])smem;          // [96][17]
    const int nb = bid & 31, ib = bid >> 5;
    const int i_loc = t >> 4, n_loc = t & 15;
    const int n0 = nb * 16, i0 = ib * 16;

    const float* z = fsl + ((size_t)(i0 + i_loc) * N_SZ + (n0 + n_loc)) * D_SZ;
    float v[D_SZ], s[D_SZ];
#pragma unroll
    for (int d = 0; d < D_SZ; ++d) { v[d] = z[d]; s[d] = v[d]; }
#define CSWAP(a, b) { float hi = fmaxf(s[a], s[b]); float lo = fminf(s[a], s[b]); s[a] = hi; s[b] = lo; }
#pragma unroll
    for (int r = 0; r < 3; ++r) {
      CSWAP(0, 1) CSWAP(2, 3) CSWAP(4, 5)
      CSWAP(1, 2) CSWAP(3, 4)
    }
#undef CSWAP
    float cs[D_SZ];
    cs[0] = s[0];
#pragma unroll
    for (int j = 1; j < D_SZ; ++j) cs[j] = cs[j - 1] + s[j];
    int kz = 0;
#pragma unroll
    for (int j = 0; j < D_SZ; ++j)
      kz += (1.0f + (float)(j + 1) * s[j] > cs[j]) ? 1 : 0;
    const float tau = (cs[kz - 1] - 1.0f) / (float)kz;
#pragma unroll
    for (int d = 0; d < D_SZ; ++d)
      sT[n_loc * 6 + d][i_loc] = fmaxf(v[d] - tau, 0.0f);
    __syncthreads();

    if (t < 192) {
      const int r = t >> 1, h = t & 1;             // r: 96 k' rows, h: i half
      const int g  = 6 * nb + (r >> 4), lm = r & 15;
      const int kk = ib >> 1, q = (ib & 1) * 2 + h;
      bf16x8 o;
#pragma unroll
      for (int jj = 0; jj < 8; ++jj) o[jj] = (bf16_t)sT[r][h * 8 + jj];
      *(bf16x8*)(selF + ((size_t)(g * 8 + kk) * 64 + q * 16 + lm) * 8) = o;
    }
  } else if (bid < 576) {
    // ---- x pack: 16 b rows -> 8 frags x 64 lanes = 512 writes (2 rounds)
    float (*xs)[257] = (float(*)[257])smem;        // [16][257]
    const int gb = bid - 512;
#pragma unroll
    for (int c = 0; c < 4; ++c) {
      const int e = c * 256 + t;                   // float4 index, 64 per row
      const int row = e >> 6, col = (e & 63) * 4;
      const float4 v = *(const float4*)(x + (size_t)(gb * 16 + row) * I_SZ + col);
      xs[row][col] = v.x; xs[row][col + 1] = v.y;
      xs[row][col + 2] = v.z; xs[row][col + 3] = v.w;
    }
    __syncthreads();
#pragma unroll
    for (int h = 0; h < 2; ++h) {
      const int fid = h * 256 + t;                 // 0..511
      const int kk = fid >> 6, lane = fid & 63;
      const int lm = lane & 15, q = lane >> 4;
      bf16x8 o;
#pragma unroll
      for (int jj = 0; jj < 8; ++jj) o[jj] = (bf16_t)xs[lm][kk * 32 + q * 8 + jj];
      *(bf16x8*)(xbF + ((size_t)(gb * 8 + kk) * 64 + lane) * 8) = o;
    }
  } else if (bid < 704) {
    // ---- resp pack: 4 n rows -> 4n x 2chunk x 64lane = 512 writes (2 rounds)
    float (*rs)[16][65] = (float(*)[16][65])smem;  // [4][16][65]
    const int n0 = (bid - 576) * 4;
#pragma unroll
    for (int c = 0; c < 4; ++c) {
      const int e = c * 256 + t;                   // float4 index, 256 per n
      const int n_loc = e >> 8, idx = (e & 255) * 4;
      const int u = idx >> 6, cc = idx & 63;
      const float4 v = *(const float4*)(resp + (size_t)(n0 + n_loc) * 1024 + idx);
      rs[n_loc][u][cc] = v.x; rs[n_loc][u][cc + 1] = v.y;
      rs[n_loc][u][cc + 2] = v.z; rs[n_loc][u][cc + 3] = v.w;
    }
    __syncthreads();
#pragma unroll
    for (int h = 0; h < 2; ++h) {
      const int fid = h * 256 + t;                 // 0..511
      const int n_loc = fid >> 7, chunk = (fid >> 6) & 1, lane = fid & 63;
      const int lm = lane & 15, q = lane >> 4;
      bf16x8 o;
#pragma unroll
      for (int jj = 0; jj < 8; ++jj)
        o[jj] = (bf16_t)rs[n_loc][lm][chunk * 32 + q * 8 + jj];
      *(bf16x8*)(respF + ((size_t)((n0 + n_loc) * 2 + chunk) * 64 + lane) * 8) = o;
    }
  } else if (bid < 720) {
    // ---- zero out[1024][16]
    const int idx = ((bid - 704) * 256 + t) * 4;
    *(float4*)(out + idx) = make_float4(0.f, 0.f, 0.f, 0.f);
  } else {
    // ---- sb: tl = fv*scale + bias with scale=exp(-lt), bias=-th*scale
    const int i = (bid - 720) * 256 + t;           // < 3072
    const float sc = __expf(-lt[i]);
    sb[i] = make_float2(sc, -th[i] * sc);
  }
}

// ---------------------------------------------------------------------------
// fused_k: block (btile, ns) owns b in [btile*64,+64), n in [ns*8,+8).
//  Phase A (all 4 waves): wave w = b-subtile, 3 k'-group accumulators;
//    24 MFMA + 32 coalesced 1-KB frag loads. Epilogue: single fma with
//    precomputed sb (R10 did 12 __expf + 24 scattered th/lt loads per thread
//    on the pre-barrier critical path). respF frags for n=0..3 are
//    register-prefetched BEFORE the barrier (loads can't be compiler-hoisted
//    across __syncthreads) so Phase B starts compute-ready; n=4..7 loads
//    hide behind n=0..3's VALU work.
//  Phase B: bins from LDS fv, per-lane leaf-weight A-frags (c-bits: jj=0-2
//    frag elem, q=3-4 lane quad, chunk=5), 2 MFMA per n, atomicAdd into out
//    (C-layout => 4 lines per atomic instr; 64K line-ops total).
// ---------------------------------------------------------------------------
__global__ __launch_bounds__(256, 4) void fused_k(
    const bf16_t* __restrict__ selF,  // packed [192][8][64][8]
    const bf16_t* __restrict__ xbF,   // packed [64][8][64][8]
    const float2* __restrict__ sb,    // [3072] (scale, bias)
    const bf16_t* __restrict__ respF, // packed [512][2][64][8]
    float* __restrict__ out) {        // [1024 b][16 u], pre-zeroed by prep
  __shared__ float fv[48][68];        // [k'_loc][b_loc], pad 68
  const int t = threadIdx.x;
  const int lane = t & 63, wave = t >> 6;
  const int lm = lane & 15, q = lane >> 4;
  const int btile = blockIdx.x & 15, ns = blockIdx.x >> 4;

  // ---- Phase A: GEMM 48 k' x 64 b; wave w = b-subtile w
  bf16x8 rpre[8];   // respF frags for n = ns*8 + 0..3 (both chunks)
  {
    f32x4 acc[3];
#pragma unroll
    for (int kg = 0; kg < 3; ++kg) acc[kg] = (f32x4){0.f, 0.f, 0.f, 0.f};
    const bf16_t* aF = selF + ((size_t)(ns * 3) * 8 * 64 + lane) * 8;
    const bf16_t* bF = xbF + ((size_t)(btile * 4 + wave) * 8 * 64 + lane) * 8;
#pragma unroll
    for (int kk = 0; kk < 8; ++kk) {
      const bf16x8 bv = *(const bf16x8*)(bF + (size_t)kk * 64 * 8);
#pragma unroll
      for (int kg = 0; kg < 3; ++kg) {
        const bf16x8 a = *(const bf16x8*)(aF + (size_t)(kg * 8 + kk) * 64 * 8);
        acc[kg] = __builtin_amdgcn_mfma_f32_16x16x32_bf16(a, bv, acc[kg], 0, 0, 0);
      }
    }

    // prefetch Phase B's first-half respF frags (issue before the barrier)
    const bf16_t* rF0 = respF + ((size_t)(ns * 8) * 2 * 64 + lane) * 8;
#pragma unroll
    for (int p = 0; p < 8; ++p)
      rpre[p] = *(const bf16x8*)(rF0 + (size_t)p * 64 * 8);

    // C/D: row(k'_loc) = kg*16 + q*4 + r, col(b_loc) = wave*16 + lm
#pragma unroll
    for (int kg = 0; kg < 3; ++kg)
#pragma unroll
      for (int r = 0; r < 4; ++r) {
        const float2 sv = sb[ns * 48 + kg * 16 + q * 4 + r];
        fv[kg * 16 + q * 4 + r][wave * 16 + lm] = fmaf(acc[kg][r], sv.x, sv.y);
      }
  }
  __syncthreads();

  // ---- Phase B: tree eval; wave handles b_loc in [wave*16, +16)
  f32x4 acc = (f32x4){0.f, 0.f, 0.f, 0.f};
  const int bloc = wave * 16 + lm;

#pragma unroll
  for (int j = 0; j < 8; ++j) {
    const int n = ns * 8 + j;
    bf16x8 bv0, bv1;
    if (j < 4) {
      bv0 = rpre[j * 2]; bv1 = rpre[j * 2 + 1];
    } else {
      const bf16_t* rF = respF + ((size_t)n * 2 * 64 + lane) * 8;
      bv0 = *(const bf16x8*)(rF);
      bv1 = *(const bf16x8*)(rF + 64 * 8);
    }

    float b0v[D_SZ], b1v[D_SZ];
#pragma unroll
    for (int d = 0; d < D_SZ; ++d) {
      const float tl = fv[j * 6 + d][bloc];
      b1v[d] = fminf(fmaxf(0.5f * tl + 0.5f, 0.0f), 1.0f);  // bit = 0
      b0v[d] = fminf(fmaxf(0.5f - 0.5f * tl, 0.0f), 1.0f);  // bit = 1
    }
    float p2[2], p4[4], p8[8];
    p2[0] = b1v[0]; p2[1] = b0v[0];
#pragma unroll
    for (int i = 0; i < 4; ++i) p4[i] = p2[i & 1] * ((i & 2) ? b0v[1] : b1v[1]);
#pragma unroll
    for (int i = 0; i < 8; ++i) p8[i] = p4[i & 3] * ((i & 4) ? b0v[2] : b1v[2]);
    const float f3 = (q & 1) ? b0v[3] : b1v[3];
    const float f4 = (q & 2) ? b0v[4] : b1v[4];
    const float fq = f3 * f4;
    const float g0 = fq * b1v[5];   // chunk 0: bit5 = 0
    const float g1 = fq * b0v[5];   // chunk 1: bit5 = 1

    bf16x8 a0, a1;
#pragma unroll
    for (int jj = 0; jj < 8; ++jj) {
      a0[jj] = (bf16_t)(p8[jj] * g0);
      a1[jj] = (bf16_t)(p8[jj] * g1);
    }
    acc = __builtin_amdgcn_mfma_f32_16x16x32_bf16(a0, bv0, acc, 0, 0, 0);
    acc = __builtin_amdgcn_mfma_f32_16x16x32_bf16(a1, bv1, acc, 0, 0, 0);
  }

  // C/D: col(u) = lm, row(b within 16) = q*4 + r; accumulate over ns-blocks
  float* obase = out + (size_t)(btile * 64 + wave * 16) * U_SZ;
#pragma unroll
  for (int r = 0; r < 4; ++r)
    atomicAdd(&obase[(q * 4 + r) * U_SZ + lm], acc[r]);
}

// ---------------------------------------------------------------------------
extern "C" void kernel_launch(void* const* d_in, const int* in_sizes, int n_in,
                              void* d_out, int out_size, void* d_ws, size_t ws_size,
                              hipStream_t stream) {
  const float* x    = (const float*)d_in[0];
  const float* fsl  = (const float*)d_in[1];
  const float* th   = (const float*)d_in[2];
  const float* lt   = (const float*)d_in[3];
  const float* resp = (const float*)d_in[4];
  float* out = (float*)d_out;

  char* w = (char*)d_ws;
  bf16_t* selF  = (bf16_t*)(w);                 // 1572864 B  packed sel
  bf16_t* xbF   = (bf16_t*)(w + 1572864);       //  524288 B  packed x
  bf16_t* respF = (bf16_t*)(w + 2097152);       // 1048576 B  packed resp
  float2* sb    = (float2*)(w + 3145728);       //   24576 B  (scale, bias)

  // 0) pack all MFMA operands + sb + zero out
  prep_pack<<<732, 256, 0, stream>>>(fsl, x, resp, th, lt,
                                     selF, xbF, respF, sb, out);

  // 1) fused GEMM + tree eval, atomic-accumulated into out (1024 blocks)
  fused_k<<<16 * NSPLIT, 256, 0, stream>>>(selF, xbF, sb, respF, out);
}